// Round 13
// baseline (374.961 us; speedup 1.0000x reference)
//
#include <hip/hip_runtime.h>
#include <cstdint>
#include <cstddef>

// ---------------------------------------------------------------------------
// feature_matching: corr(P=20, C=64) -> 4x (depthwise 3^3 + pointwise) blocks
//
// R13 = R12 with phase-1 register double-buffering in fused_impl. R12: fb1
// VALUBusy 56%/occ 47% with VGPR 44 -> compiler serialized planes (one
// 24-load batch in flight). v10: explicit Rb[2] buffers, load batch bi+1
// before computing batch bi (d/h-clamped addresses, masks at compute) ->
// ~48 loads in flight, plane-boundary stalls gone. pw-weight gather hoisted
// above phase 1 when NT*KH<=4. __launch_bounds__(256,4) caps VGPR at 128.
// corr v5 + XCD swizzle unchanged from R12.
//
// ws layout (peak 157,286,400 B):
//   [0,        78.6MB): corrO (f16)        -> later b2o (f16, 19.7MB)
//   [78.6MB,  157.3MB): rgbT+depT (f16)    -> later b1o (f16, 78.6MB)
//                                          -> later b3o (f16, 19.7MB)
// ---------------------------------------------------------------------------

typedef unsigned short u16;
typedef _Float16 f16_t;
typedef __attribute__((ext_vector_type(2))) _Float16 half2_t;
typedef __attribute__((ext_vector_type(8))) _Float16 half8_t;
typedef __attribute__((ext_vector_type(4))) float f32x4;

static __device__ inline u16 f2h(float f) {
    union { f16_t h; u16 u; } v; v.h = (f16_t)f; return v.u;
}
static __device__ inline half2_t H2(uint32_t u) {
    union { uint32_t u; half2_t h; } v; v.u = u; return v.h;
}

#if __has_builtin(__builtin_amdgcn_fdot2)
static __device__ inline float FDOT2(half2_t a, half2_t b, float c) {
    return __builtin_amdgcn_fdot2(a, b, c, false);
}
#else
static __device__ inline float FDOT2(half2_t a, half2_t b, float c) {
    return fmaf((float)a.x, (float)b.x, fmaf((float)a.y, (float)b.y, c));
}
#endif

#if __has_builtin(__builtin_amdgcn_alignbit)
static __device__ inline uint32_t mkp(uint32_t lo, uint32_t hi) {
    return __builtin_amdgcn_alignbit(hi, lo, 16);   // (lo.hi16, hi.lo16)
}
#else
static __device__ inline uint32_t mkp(uint32_t lo, uint32_t hi) {
    return (lo >> 16) | (hi << 16);
}
#endif

static __device__ inline uint32_t ldu(const u16* p) { return *(const uint32_t*)p; }

// ---------------------------------------------------------------------------
// Prepass: (b,c,h,w) fp32 -> (b,h,w,c) f16, LDS tile transpose per (b,h).
// ---------------------------------------------------------------------------
__global__ __launch_bounds__(256) void transpose_f16(
        const float* __restrict__ rgb, const float* __restrict__ dep,
        u16* __restrict__ rgbT, u16* __restrict__ depT) {
    const int bh = blockIdx.x;
    const float* src = blockIdx.y ? dep : rgb;
    u16* dst = blockIdx.y ? depT : rgbT;
    const int tid = threadIdx.x;
    const int b = bh >> 6, h = bh & 63;

    __shared__ u16 S[64 * 194];

    const float* srcb = src + (size_t)b * 786432 + (size_t)h * 192;
#pragma unroll
    for (int it = 0; it < 12; ++it) {
        const int idx = it * 256 + tid;      // 3072 = 64c x 48 float4
        const int c = idx / 48, w4 = idx - c * 48;
        const float4 v = *(const float4*)(srcb + (size_t)c * 12288 + 4 * w4);
        u16* sp = &S[c * 194 + 4 * w4];
        sp[0] = f2h(v.x); sp[1] = f2h(v.y); sp[2] = f2h(v.z); sp[3] = f2h(v.w);
    }
    __syncthreads();
    u16* dstb = dst + (size_t)bh * 192 * 64;
#pragma unroll
    for (int it = 0; it < 12; ++it) {
        const int idx = it * 256 + tid;      // 3072 = 192w x 16 c4
        const int w = idx >> 4, c4 = idx & 15;
        ushort4 o;
        o.x = S[(4 * c4 + 0) * 194 + w];
        o.y = S[(4 * c4 + 1) * 194 + w];
        o.z = S[(4 * c4 + 2) * 194 + w];
        o.w = S[(4 * c4 + 3) * 194 + w];
        *(ushort4*)(dstb + (size_t)w * 64 + 4 * c4) = o;
    }
}

// ---------------------------------------------------------------------------
// corr v5 (unchanged from R12). Flat grid 2560, XCD-band swizzle.
// ---------------------------------------------------------------------------
__global__ __launch_bounds__(256) void corr_mfma(
        const u16* __restrict__ rgbT, const u16* __restrict__ depT,
        u16* __restrict__ out) {
    const int idx = blockIdx.x;
    const int band = idx & 7;
    const int j    = idx >> 3;
    const int dig  = j % 5;
    const int rest = j / 5;          // 0..63
    const int h    = band * 8 + (rest & 7);
    const int b    = rest >> 3;
    const int tid = threadIdx.x;
    const int lane = tid & 63, wave = tid >> 6;
    const int n = lane & 15, q = lane >> 4;
    const int w0base = wave * 48;

    __shared__ u16 D4[4][4080];      // per-di bank; addr = w*21 + (w>>2) + dj

    const u16* Abase = rgbT + (size_t)(b * 64 + h) * 12288;
    half8_t a0[3], a1[3];
#pragma unroll
    for (int t = 0; t < 3; ++t) {
        const half8_t* Ap = (const half8_t*)(Abase + (size_t)(w0base + t * 16 + n) * 64 + q * 8);
        a0[t] = Ap[0];               // c = q*8 .. q*8+7
        a1[t] = Ap[4];               // c += 32
    }

#pragma unroll
    for (int i = 0; i < 4; ++i) {
        const int di = dig * 4 + i;
        const int hd = h + di - 10;
        if (hd < 0 || hd >= 64) continue;    // block-uniform; zeros at readout

        const u16* Bbase = depT + (size_t)(b * 64 + hd) * 12288;
        half8_t B0[5], B1[5];
#pragma unroll
        for (int k = 0; k < 5; ++k) {
            const int u0 = w0base + (k - 1) * 16;
            if (u0 >= 0 && u0 <= 176) {      // wave-uniform
                const half8_t* Bp = (const half8_t*)(Bbase + (size_t)(u0 + n) * 64 + q * 8);
                B0[k] = Bp[0];
                B1[k] = Bp[4];
            } else {
                B0[k] = (half8_t)(f16_t)0.f;
                B1[k] = (half8_t)(f16_t)0.f;
            }
        }
#pragma unroll
        for (int t = 0; t < 3; ++t) {
            const int w0 = w0base + t * 16;
            f32x4 acc[3];
#pragma unroll
            for (int ut = 0; ut < 3; ++ut) {
                acc[ut].x = 0.f; acc[ut].y = 0.f; acc[ut].z = 0.f; acc[ut].w = 0.f;
            }
#pragma unroll
            for (int ut = 0; ut < 3; ++ut) {
                const int k = t + ut;        // array index for u-tile t+ut-1
                acc[ut] = __builtin_amdgcn_mfma_f32_16x16x32_f16(a0[t], B0[k], acc[ut], 0, 0, 0);
                acc[ut] = __builtin_amdgcn_mfma_f32_16x16x32_f16(a1[t], B1[k], acc[ut], 0, 0, 0);
            }
#pragma unroll
            for (int ut = 0; ut < 3; ++ut) {
#pragma unroll
                for (int r = 0; r < 4; ++r) {
                    const int dj = 16 * ut + n - 4 * q - r - 6;
                    const int w = w0 + 4 * q + r;
                    if (dj >= 0 && dj < 20)
                        D4[i][w * 21 + (w >> 2) + dj] = f2h(acc[ut][r]);
                }
            }
        }
    }

#pragma unroll
    for (int i = 0; i < 4; ++i) {
        const int di = dig * 4 + i;
        const int hd = h + di - 10;
        const bool valid = (hd >= 0) && (hd < 64);   // block-uniform
        u16* outb = out + ((size_t)((b * 20 + di) * 20) * 64 + h) * 192;
#pragma unroll
        for (int it = 0; it < 4; ++it) {
            const int item = it * 64 + lane;
            if (item < 240) {
                const int dj = item / 12;
                const int w4 = wave * 12 + (item - dj * 12);
                ushort4 o;
                if (valid) {
                    const int base = 85 * w4 + dj;   // (4*w4+j)*21 + w4 + dj
                    o.x = D4[i][base];
                    o.y = D4[i][base + 21];
                    o.z = D4[i][base + 42];
                    o.w = D4[i][base + 63];
                } else {
                    o = make_ushort4(0, 0, 0, 0);
                }
                *(ushort4*)(outb + (size_t)dj * 12288 + 4 * w4) = o;
            }
        }
    }
}

// ---------------------------------------------------------------------------
// Fused block v10. Phase 1: batches (plane, row-group) with REGISTER DOUBLE
// BUFFER — load batch bi+1 (d/h-clamped addrs) before computing batch bi.
// S=1: 1 batch/plane (6 rows x 4 dw); S=2: 3 batches/plane (3 rows x 5 dw).
// Compute skipped (block-uniform) for invalid planes; masks as R12.
// Phase 2: f16 MFMA; pw-weight gather hoisted pre-phase-1 when NT*KH<=4.
// ---------------------------------------------------------------------------
template<int CIN, int COUT, int S, int DT, int DIN, int HIN, int WIN,
         int DO, int HO, int WO, typename TOUT>
static __device__ __forceinline__ void fused_impl(
        const u16* __restrict__ x,
        const float* __restrict__ dw_w, const float* __restrict__ dw_b,
        const float* __restrict__ pw_w, const float* __restrict__ pw_b,
        TOUT* __restrict__ y) {
    static_assert(WO % 48 == 0 && HO % 4 == 0, "tile divisibility");
    constexpr int CINP = (CIN == 20) ? 22 : 42;    // odd dword stride
    constexpr int NTASK = CIN * 12;
    constexpr int WT = WO / 48;
    constexpr int NP = S * (DT - 1) + 3;
    constexpr int ROWS = 3 * S + 3;                // 6 or 9
    constexpr int NL = (S == 1) ? 4 : 5;           // dwords per row
    constexpr int G  = (S == 1) ? 6 : 3;           // rows per load batch
    constexpr int NG = ROWS / G;
    constexpr int NB = NP * NG;                    // total batches
    constexpr int NT = (COUT + 15) / 16;
    constexpr int KH = (CIN + 31) / 32;

    const int wt = blockIdx.x % WT;
    const int ht = blockIdx.x / WT;
    const int d0 = blockIdx.y * DT;
    const int b  = blockIdx.z;
    const int tid = threadIdx.x;
    const int h0 = ht * 4;
    const int wbase = wt * 48;

    __shared__ float sDW[CIN * 27];
    __shared__ float sDB[CIN];
    __shared__ u16   sT[DT * 4 * 48 * CINP + 16];

    for (int i = tid; i < CIN * 27; i += 256) sDW[i] = dw_w[i];
    for (int i = tid; i < CIN; i += 256) sDB[i] = dw_b[i];

    const int lane = tid & 63, wave = tid >> 6;
    const int m15 = lane & 15, q = lane >> 4;

    half8_t bf[NT][KH];
    float   pb[NT];
    auto gather_w = [&]() {
#pragma unroll
        for (int nt = 0; nt < NT; ++nt) {
            const int co = nt * 16 + m15;
            pb[nt] = (co < COUT) ? pw_b[co] : 0.f;
#pragma unroll
            for (int kh = 0; kh < KH; ++kh) {
                union { half8_t v; f16_t e[8]; } u;
#pragma unroll
                for (int jj = 0; jj < 8; ++jj) {
                    const int ci = kh * 32 + q * 8 + jj;
                    u.e[jj] = (co < COUT && ci < CIN)
                              ? (f16_t)pw_w[co * CIN + ci] : (f16_t)0.f;
                }
                bf[nt][kh] = u.v;
            }
        }
    };
    if constexpr (NT * KH <= 4) gather_w();   // overlap gather with phase 1
    __syncthreads();

    // ---------------- phase 1: depthwise via fdot2, dbuf batches ----------
    for (int idx = tid; idx < NTASK; idx += 256) {
        const int ci = idx / 12;
        const int wg = idx - ci * 12;
        const int w0g = wbase + wg * 4;
        const int offA = (w0g > 0) ? -2 : 0;   // keeps corner load in-bounds

        half2_t KA[9], KB[9];
#pragma unroll
        for (int t = 0; t < 9; ++t) {
            const int kd = t / 3, kh = t - 3 * kd;
            const float k0 = sDW[ci * 27 + kd * 9 + kh * 3 + 0];
            const float k1 = sDW[ci * 27 + kd * 9 + kh * 3 + 1];
            const float k2 = sDW[ci * 27 + kd * 9 + kh * 3 + 2];
            half2_t a; a.x = (f16_t)k0; a.y = (f16_t)k1; KA[t] = a;
            half2_t bb;
            if constexpr (S == 1) { bb.x = (f16_t)k2; bb.y = (f16_t)0.f; }
            else                  { bb.x = (f16_t)0.f; bb.y = (f16_t)k2; }
            KB[t] = bb;
        }

        float acc[DT][4][4];
#pragma unroll
        for (int dl = 0; dl < DT; ++dl)
#pragma unroll
            for (int a = 0; a < 4; ++a)
#pragma unroll
                for (int c = 0; c < 4; ++c) acc[dl][a][c] = 0.f;

        const u16* plane0 = x + (size_t)(b * CIN + ci) * DIN * HIN * WIN;

        uint32_t Rb[2][G * NL];

        auto load_batch = [&](int bi, uint32_t* R) {
            const int p = bi / NG;
            const int g = bi - p * NG;
            int din = S * d0 - 1 + p;
            int dc = din < 0 ? 0 : (din >= DIN ? DIN - 1 : din);
            const u16* pl = plane0 + (size_t)dc * HIN * WIN;
#pragma unroll
            for (int rr = 0; rr < G; ++rr) {
                const int r = g * G + rr;
                int hin = h0 * S - 1 + r;
                int hc = hin < 0 ? 0 : (hin >= HIN ? HIN - 1 : hin);
                const u16* rowp = pl + (size_t)hc * WIN + (size_t)w0g * S;
                R[rr * NL + 0] = ldu(rowp + offA);
                R[rr * NL + 1] = ldu(rowp);
                R[rr * NL + 2] = ldu(rowp + 2);
                R[rr * NL + 3] = ldu(rowp + 4);
                if constexpr (S == 2) R[rr * NL + 4] = ldu(rowp + 6);
            }
        };

        auto compute_batch = [&](int bi, const uint32_t* R) {
            const int p = bi / NG;
            const int g = bi - p * NG;
            const int din = S * d0 - 1 + p;
            if (din < 0 || din >= DIN) return;     // block-uniform
#pragma unroll
            for (int rr = 0; rr < G; ++rr) {
                const int r = g * G + rr;
                const int hin = h0 * S - 1 + r;
                uint32_t D0 = R[rr * NL + 0], D1 = R[rr * NL + 1];
                uint32_t D2 = R[rr * NL + 2], D3 = R[rr * NL + 3];
                uint32_t E4 = 0;
                if constexpr (S == 2) E4 = R[rr * NL + 4];
                D0 = (w0g > 0) ? D0 : 0u;
                if constexpr (S == 1) D3 = (w0g + 4 < WIN) ? D3 : 0u;
                if constexpr (S == 1) {
                    if (r == 0 || r == ROWS - 1) {
                        const bool rv = (hin >= 0) && (hin < HIN);
                        if (!rv) { D0 = 0; D1 = 0; D2 = 0; D3 = 0; }
                    }
                } else {
                    if (r == 0) {
                        const bool rv = (hin >= 0);
                        if (!rv) { D0 = 0; D1 = 0; D2 = 0; D3 = 0; E4 = 0; }
                    }
                }
                uint32_t PA[4], PB[4];
                if constexpr (S == 1) {
                    const uint32_t m01 = mkp(D0, D1);  // (x-1,x0)
                    const uint32_t m12 = mkp(D1, D2);  // (x1,x2)
                    const uint32_t m23 = mkp(D2, D3);  // (x3,x4)
                    PA[0] = m01; PA[1] = D1; PA[2] = m12; PA[3] = D2;
                    PB[0] = m12; PB[1] = D2; PB[2] = m23; PB[3] = D3;
                } else {
                    PA[0] = mkp(D0, D1); PA[1] = mkp(D1, D2);
                    PA[2] = mkp(D2, D3); PA[3] = mkp(D3, E4);
                    PB[0] = D1; PB[1] = D2; PB[2] = D3; PB[3] = E4;
                }
#pragma unroll
                for (int dl = 0; dl < DT; ++dl) {
                    const int kd = p - S * dl;         // folds after unroll
                    if (kd < 0 || kd > 2) continue;
#pragma unroll
                    for (int hh = 0; hh < 4; ++hh) {
                        const int kh = r - S * hh;     // folds after unroll
                        if (kh < 0 || kh > 2) continue;
                        const int t = kd * 3 + kh;
#pragma unroll
                        for (int k = 0; k < 4; ++k)
                            acc[dl][hh][k] = FDOT2(H2(PB[k]), KB[t],
                                             FDOT2(H2(PA[k]), KA[t],
                                                   acc[dl][hh][k]));
                    }
                }
            }
        };

        load_batch(0, Rb[0]);
#pragma unroll
        for (int bi = 0; bi < NB; ++bi) {
            if (bi + 1 < NB) load_batch(bi + 1, Rb[(bi + 1) & 1]);
            compute_batch(bi, Rb[bi & 1]);
        }

        const float bia = sDB[ci];
#pragma unroll
        for (int dl = 0; dl < DT; ++dl) {
#pragma unroll
            for (int hh = 0; hh < 4; ++hh) {
#pragma unroll
                for (int k = 0; k < 4; ++k) {
                    const float t = acc[dl][hh][k] + bia;
                    sT[((dl * 4 + hh) * 48 + wg * 4 + k) * CINP + ci] =
                        f2h(fmaxf(t, 0.1f * t));
                }
            }
        }
    }
    if constexpr (NT * KH > 4) gather_w();
    __syncthreads();

    // ---------------- phase 2: pointwise via f16 MFMA ----------------
    constexpr int MTW = DT * 3;            // M-tiles per wave
    const size_t planeSz = (size_t)DO * HO * WO;
    for (int mt = wave * MTW; mt < (wave + 1) * MTW; ++mt) {
        const int dl  = mt / 12;
        const int rem = mt - dl * 12;
        const int hh  = rem / 3;
        const int w0  = (rem - hh * 3) * 16;
        if (d0 + dl >= DO) continue;           // tail guard

        const int pos0 = (dl * 4 + hh) * 48 + w0 + m15;
        const u16* ap = &sT[(size_t)pos0 * CINP];
        union { uint32_t u[4]; half8_t v; } af[KH];
#pragma unroll
        for (int kh = 0; kh < KH; ++kh) {
            const int ci0 = kh * 32 + q * 8;
            af[kh].u[0] = (ci0     < CIN) ? ldu(ap + ci0)     : 0u;
            af[kh].u[1] = (ci0 + 2 < CIN) ? ldu(ap + ci0 + 2) : 0u;
            af[kh].u[2] = (ci0 + 4 < CIN) ? ldu(ap + ci0 + 4) : 0u;
            af[kh].u[3] = (ci0 + 6 < CIN) ? ldu(ap + ci0 + 6) : 0u;
        }
#pragma unroll
        for (int nt = 0; nt < NT; ++nt) {
            f32x4 acc;
            acc.x = 0.f; acc.y = 0.f; acc.z = 0.f; acc.w = 0.f;
#pragma unroll
            for (int kh = 0; kh < KH; ++kh)
                acc = __builtin_amdgcn_mfma_f32_16x16x32_f16(
                          af[kh].v, bf[nt][kh], acc, 0, 0, 0);
            const int co = nt * 16 + m15;
            if (co < COUT) {
                const float bias = pb[nt];
                TOUT* yp = y + (size_t)b * COUT * planeSz + (size_t)co * planeSz
                             + (size_t)(d0 + dl) * HO * WO
                             + (size_t)(h0 + hh) * WO + wbase + w0 + q * 4;
                float s0 = acc.x + bias, s1 = acc.y + bias;
                float s2 = acc.z + bias, s3 = acc.w + bias;
                s0 = fmaxf(s0, 0.1f * s0); s1 = fmaxf(s1, 0.1f * s1);
                s2 = fmaxf(s2, 0.1f * s2); s3 = fmaxf(s3, 0.1f * s3);
                if constexpr (sizeof(TOUT) == 4) {
                    float4 o; o.x = s0; o.y = s1; o.z = s2; o.w = s3;
                    *(float4*)yp = o;
                } else {
                    ushort4 o;
                    o.x = f2h(s0); o.y = f2h(s1); o.z = f2h(s2); o.w = f2h(s3);
                    *(ushort4*)yp = o;
                }
            }
        }
    }
}

// Named wrappers -> per-stage visibility in rocprof.
__global__ __launch_bounds__(256, 4) void fb1_dwpw(
        const u16* __restrict__ x, const float* __restrict__ dww,
        const float* __restrict__ dwb, const float* __restrict__ pww,
        const float* __restrict__ pwb, u16* __restrict__ y) {
    fused_impl<20, 20, 1, 2, 20, 64, 192, 20, 64, 192, u16>(x, dww, dwb, pww, pwb, y);
}
__global__ __launch_bounds__(256, 4) void fb2_dwpw(
        const u16* __restrict__ x, const float* __restrict__ dww,
        const float* __restrict__ dwb, const float* __restrict__ pww,
        const float* __restrict__ pwb, u16* __restrict__ y) {
    fused_impl<20, 40, 2, 2, 20, 64, 192, 10, 32, 96, u16>(x, dww, dwb, pww, pwb, y);
}
__global__ __launch_bounds__(256, 4) void fb3_dwpw(
        const u16* __restrict__ x, const float* __restrict__ dww,
        const float* __restrict__ dwb, const float* __restrict__ pww,
        const float* __restrict__ pwb, u16* __restrict__ y) {
    fused_impl<40, 40, 1, 1, 10, 32, 96, 10, 32, 96, u16>(x, dww, dwb, pww, pwb, y);
}
__global__ __launch_bounds__(256, 4) void fb4_dwpw(
        const u16* __restrict__ x, const float* __restrict__ dww,
        const float* __restrict__ dwb, const float* __restrict__ pww,
        const float* __restrict__ pwb, float* __restrict__ y) {
    fused_impl<40, 80, 2, 1, 10, 32, 96, 5, 16, 48, float>(x, dww, dwb, pww, pwb, y);
}

// ---------------------------------------------------------------------------
extern "C" void kernel_launch(void* const* d_in, const int* in_sizes, int n_in,
                              void* d_out, int out_size, void* d_ws, size_t ws_size,
                              hipStream_t stream) {
    const float* rgb  = (const float*)d_in[0];
    const float* dep  = (const float*)d_in[1];
    const float* dw1w = (const float*)d_in[2];
    const float* dw1b = (const float*)d_in[3];
    const float* pw1w = (const float*)d_in[4];
    const float* pw1b = (const float*)d_in[5];
    const float* dw2w = (const float*)d_in[6];
    const float* dw2b = (const float*)d_in[7];
    const float* pw2w = (const float*)d_in[8];
    const float* pw2b = (const float*)d_in[9];
    const float* dw3w = (const float*)d_in[10];
    const float* dw3b = (const float*)d_in[11];
    const float* pw3w = (const float*)d_in[12];
    const float* pw3b = (const float*)d_in[13];
    const float* dw4w = (const float*)d_in[14];
    const float* dw4b = (const float*)d_in[15];
    const float* pw4w = (const float*)d_in[16];
    const float* pw4b = (const float*)d_in[17];

    const size_t HALF = 78643200;
    u16* corrO = (u16*)d_ws;
    u16* rgbT  = (u16*)((char*)d_ws + HALF);
    u16* depT  = (u16*)((char*)d_ws + HALF + 12582912);
    u16* b1o   = (u16*)((char*)d_ws + HALF);   // rgbT/depT dead by then
    u16* b2o   = (u16*)d_ws;                   // corrO dead by then
    u16* b3o   = (u16*)((char*)d_ws + HALF);   // b1o dead by then
    float* outp = (float*)d_out;

    transpose_f16<<<dim3(512, 2), 256, 0, stream>>>(rgb, dep, rgbT, depT);

    corr_mfma<<<dim3(2560), 256, 0, stream>>>(rgbT, depT, corrO);

    fb1_dwpw<<<dim3(64, 10, 8), 256, 0, stream>>>(corrO, dw1w, dw1b, pw1w, pw1b, b1o);
    fb2_dwpw<<<dim3(16, 5, 8), 256, 0, stream>>>(b1o, dw2w, dw2b, pw2w, pw2b, b2o);
    fb3_dwpw<<<dim3(16, 10, 8), 256, 0, stream>>>(b2o, dw3w, dw3b, pw3w, pw3b, b3o);
    fb4_dwpw<<<dim3(4, 5, 8), 256, 0, stream>>>(b3o, dw4w, dw4b, pw4w, pw4b, outp);
}

// Round 14
// 358.856 us; speedup vs baseline: 1.0449x; 1.0449x over previous
//
#include <hip/hip_runtime.h>
#include <cstdint>
#include <cstddef>

// ---------------------------------------------------------------------------
// feature_matching: corr(P=20, C=64) -> 4x (depthwise 3^3 + pointwise) blocks
//
// R14 = R12 (revert of R13's register-dbuf, which spilled: WRITE 77->115MB,
// occ 47->38%) + XCD-banded d-fastest dispatch order for fb1/fb2/fb3:
// idx = band + 8*j, j = y + NY*(T>>3), T = x + NX*z. Same-plane consumer
// blocks (adjacent d-groups) become adjacent in time on one XCD -> d-halo
// refetch (fb1 FETCH 157MB = 2.0x corrO) should be absorbed by per-XCD L2.
// Pure index permutation; locality-only.
//
// ws layout (peak 157,286,400 B):
//   [0,        78.6MB): corrO (f16)        -> later b2o (f16, 19.7MB)
//   [78.6MB,  157.3MB): rgbT+depT (f16)    -> later b1o (f16, 78.6MB)
//                                          -> later b3o (f16, 19.7MB)
// ---------------------------------------------------------------------------

typedef unsigned short u16;
typedef _Float16 f16_t;
typedef __attribute__((ext_vector_type(2))) _Float16 half2_t;
typedef __attribute__((ext_vector_type(8))) _Float16 half8_t;
typedef __attribute__((ext_vector_type(4))) float f32x4;

static __device__ inline u16 f2h(float f) {
    union { f16_t h; u16 u; } v; v.h = (f16_t)f; return v.u;
}
static __device__ inline half2_t H2(uint32_t u) {
    union { uint32_t u; half2_t h; } v; v.u = u; return v.h;
}

#if __has_builtin(__builtin_amdgcn_fdot2)
static __device__ inline float FDOT2(half2_t a, half2_t b, float c) {
    return __builtin_amdgcn_fdot2(a, b, c, false);
}
#else
static __device__ inline float FDOT2(half2_t a, half2_t b, float c) {
    return fmaf((float)a.x, (float)b.x, fmaf((float)a.y, (float)b.y, c));
}
#endif

#if __has_builtin(__builtin_amdgcn_alignbit)
static __device__ inline uint32_t mkp(uint32_t lo, uint32_t hi) {
    return __builtin_amdgcn_alignbit(hi, lo, 16);   // (lo.hi16, hi.lo16)
}
#else
static __device__ inline uint32_t mkp(uint32_t lo, uint32_t hi) {
    return (lo >> 16) | (hi << 16);
}
#endif

static __device__ inline uint32_t ldu(const u16* p) { return *(const uint32_t*)p; }

// ---------------------------------------------------------------------------
// Prepass: (b,c,h,w) fp32 -> (b,h,w,c) f16, LDS tile transpose per (b,h).
// ---------------------------------------------------------------------------
__global__ __launch_bounds__(256) void transpose_f16(
        const float* __restrict__ rgb, const float* __restrict__ dep,
        u16* __restrict__ rgbT, u16* __restrict__ depT) {
    const int bh = blockIdx.x;
    const float* src = blockIdx.y ? dep : rgb;
    u16* dst = blockIdx.y ? depT : rgbT;
    const int tid = threadIdx.x;
    const int b = bh >> 6, h = bh & 63;

    __shared__ u16 S[64 * 194];

    const float* srcb = src + (size_t)b * 786432 + (size_t)h * 192;
#pragma unroll
    for (int it = 0; it < 12; ++it) {
        const int idx = it * 256 + tid;      // 3072 = 64c x 48 float4
        const int c = idx / 48, w4 = idx - c * 48;
        const float4 v = *(const float4*)(srcb + (size_t)c * 12288 + 4 * w4);
        u16* sp = &S[c * 194 + 4 * w4];
        sp[0] = f2h(v.x); sp[1] = f2h(v.y); sp[2] = f2h(v.z); sp[3] = f2h(v.w);
    }
    __syncthreads();
    u16* dstb = dst + (size_t)bh * 192 * 64;
#pragma unroll
    for (int it = 0; it < 12; ++it) {
        const int idx = it * 256 + tid;      // 3072 = 192w x 16 c4
        const int w = idx >> 4, c4 = idx & 15;
        ushort4 o;
        o.x = S[(4 * c4 + 0) * 194 + w];
        o.y = S[(4 * c4 + 1) * 194 + w];
        o.z = S[(4 * c4 + 2) * 194 + w];
        o.w = S[(4 * c4 + 3) * 194 + w];
        *(ushort4*)(dstb + (size_t)w * 64 + 4 * c4) = o;
    }
}

// ---------------------------------------------------------------------------
// corr v5 (unchanged from R12). Flat grid 2560, XCD-band swizzle.
// ---------------------------------------------------------------------------
__global__ __launch_bounds__(256) void corr_mfma(
        const u16* __restrict__ rgbT, const u16* __restrict__ depT,
        u16* __restrict__ out) {
    const int idx = blockIdx.x;
    const int band = idx & 7;
    const int j    = idx >> 3;
    const int dig  = j % 5;
    const int rest = j / 5;          // 0..63
    const int h    = band * 8 + (rest & 7);
    const int b    = rest >> 3;
    const int tid = threadIdx.x;
    const int lane = tid & 63, wave = tid >> 6;
    const int n = lane & 15, q = lane >> 4;
    const int w0base = wave * 48;

    __shared__ u16 D4[4][4080];      // per-di bank; addr = w*21 + (w>>2) + dj

    const u16* Abase = rgbT + (size_t)(b * 64 + h) * 12288;
    half8_t a0[3], a1[3];
#pragma unroll
    for (int t = 0; t < 3; ++t) {
        const half8_t* Ap = (const half8_t*)(Abase + (size_t)(w0base + t * 16 + n) * 64 + q * 8);
        a0[t] = Ap[0];               // c = q*8 .. q*8+7
        a1[t] = Ap[4];               // c += 32
    }

#pragma unroll
    for (int i = 0; i < 4; ++i) {
        const int di = dig * 4 + i;
        const int hd = h + di - 10;
        if (hd < 0 || hd >= 64) continue;    // block-uniform; zeros at readout

        const u16* Bbase = depT + (size_t)(b * 64 + hd) * 12288;
        half8_t B0[5], B1[5];
#pragma unroll
        for (int k = 0; k < 5; ++k) {
            const int u0 = w0base + (k - 1) * 16;
            if (u0 >= 0 && u0 <= 176) {      // wave-uniform
                const half8_t* Bp = (const half8_t*)(Bbase + (size_t)(u0 + n) * 64 + q * 8);
                B0[k] = Bp[0];
                B1[k] = Bp[4];
            } else {
                B0[k] = (half8_t)(f16_t)0.f;
                B1[k] = (half8_t)(f16_t)0.f;
            }
        }
#pragma unroll
        for (int t = 0; t < 3; ++t) {
            const int w0 = w0base + t * 16;
            f32x4 acc[3];
#pragma unroll
            for (int ut = 0; ut < 3; ++ut) {
                acc[ut].x = 0.f; acc[ut].y = 0.f; acc[ut].z = 0.f; acc[ut].w = 0.f;
            }
#pragma unroll
            for (int ut = 0; ut < 3; ++ut) {
                const int k = t + ut;        // array index for u-tile t+ut-1
                acc[ut] = __builtin_amdgcn_mfma_f32_16x16x32_f16(a0[t], B0[k], acc[ut], 0, 0, 0);
                acc[ut] = __builtin_amdgcn_mfma_f32_16x16x32_f16(a1[t], B1[k], acc[ut], 0, 0, 0);
            }
#pragma unroll
            for (int ut = 0; ut < 3; ++ut) {
#pragma unroll
                for (int r = 0; r < 4; ++r) {
                    const int dj = 16 * ut + n - 4 * q - r - 6;
                    const int w = w0 + 4 * q + r;
                    if (dj >= 0 && dj < 20)
                        D4[i][w * 21 + (w >> 2) + dj] = f2h(acc[ut][r]);
                }
            }
        }
    }

#pragma unroll
    for (int i = 0; i < 4; ++i) {
        const int di = dig * 4 + i;
        const int hd = h + di - 10;
        const bool valid = (hd >= 0) && (hd < 64);   // block-uniform
        u16* outb = out + ((size_t)((b * 20 + di) * 20) * 64 + h) * 192;
#pragma unroll
        for (int it = 0; it < 4; ++it) {
            const int item = it * 64 + lane;
            if (item < 240) {
                const int dj = item / 12;
                const int w4 = wave * 12 + (item - dj * 12);
                ushort4 o;
                if (valid) {
                    const int base = 85 * w4 + dj;   // (4*w4+j)*21 + w4 + dj
                    o.x = D4[i][base];
                    o.y = D4[i][base + 21];
                    o.z = D4[i][base + 42];
                    o.w = D4[i][base + 63];
                } else {
                    o = make_ushort4(0, 0, 0, 0);
                }
                *(ushort4*)(outb + (size_t)dj * 12288 + 4 * w4) = o;
            }
        }
    }
}

// ---------------------------------------------------------------------------
// Fused block v9 (R12 body, parameterized block coords for swizzled launch).
// Phase 1: load-pass (batched, unconditional, h-clamped) + compute-pass
// (masks + fdot2). Phase 2: f16 MFMA pointwise.
// ---------------------------------------------------------------------------
template<int CIN, int COUT, int S, int DT, int DIN, int HIN, int WIN,
         int DO, int HO, int WO, typename TOUT>
static __device__ __forceinline__ void fused_impl(
        const u16* __restrict__ x,
        const float* __restrict__ dw_w, const float* __restrict__ dw_b,
        const float* __restrict__ pw_w, const float* __restrict__ pw_b,
        TOUT* __restrict__ y, int bx, int by, int bz) {
    static_assert(WO % 48 == 0 && HO % 4 == 0, "tile divisibility");
    constexpr int CINP = (CIN == 20) ? 22 : 42;    // odd dword stride
    constexpr int NTASK = CIN * 12;
    constexpr int WT = WO / 48;
    constexpr int NP = S * (DT - 1) + 3;
    constexpr int ROWS = 3 * S + 3;                // 6 or 9
    constexpr int NL = (S == 1) ? 4 : 5;           // dwords per row
    constexpr int G  = (S == 1) ? 6 : 3;           // rows per load batch
    constexpr int NG = ROWS / G;

    const int wt = bx % WT;
    const int ht = bx / WT;
    const int d0 = by * DT;
    const int b  = bz;
    const int tid = threadIdx.x;
    const int h0 = ht * 4;
    const int wbase = wt * 48;

    __shared__ float sDW[CIN * 27];
    __shared__ float sDB[CIN];
    __shared__ u16   sT[DT * 4 * 48 * CINP + 16];

    for (int i = tid; i < CIN * 27; i += 256) sDW[i] = dw_w[i];
    for (int i = tid; i < CIN; i += 256) sDB[i] = dw_b[i];
    __syncthreads();

    // ---------------- phase 1: depthwise via fdot2 ----------------
    for (int idx = tid; idx < NTASK; idx += 256) {
        const int ci = idx / 12;
        const int wg = idx - ci * 12;
        const int w0g = wbase + wg * 4;
        const int offA = (w0g > 0) ? -2 : 0;   // keeps corner load in-bounds

        half2_t KA[9], KB[9];
#pragma unroll
        for (int t = 0; t < 9; ++t) {
            const int kd = t / 3, kh = t - 3 * kd;
            const float k0 = sDW[ci * 27 + kd * 9 + kh * 3 + 0];
            const float k1 = sDW[ci * 27 + kd * 9 + kh * 3 + 1];
            const float k2 = sDW[ci * 27 + kd * 9 + kh * 3 + 2];
            half2_t a; a.x = (f16_t)k0; a.y = (f16_t)k1; KA[t] = a;
            half2_t bb;
            if constexpr (S == 1) { bb.x = (f16_t)k2; bb.y = (f16_t)0.f; }
            else                  { bb.x = (f16_t)0.f; bb.y = (f16_t)k2; }
            KB[t] = bb;
        }

        float acc[DT][4][4];
#pragma unroll
        for (int dl = 0; dl < DT; ++dl)
#pragma unroll
            for (int a = 0; a < 4; ++a)
#pragma unroll
                for (int c = 0; c < 4; ++c) acc[dl][a][c] = 0.f;

        const u16* plane0 = x + (size_t)(b * CIN + ci) * DIN * HIN * WIN;
#pragma unroll
        for (int p = 0; p < NP; ++p) {
            const int din = S * d0 - 1 + p;
            if (din < 0 || din >= DIN) continue;       // block-uniform, rare
            const u16* pl = plane0 + (size_t)din * HIN * WIN;
#pragma unroll
            for (int g = 0; g < NG; ++g) {
                // ---- load pass: all rows of this batch, unconditional ----
                uint32_t R[G][NL];
#pragma unroll
                for (int rr = 0; rr < G; ++rr) {
                    const int r = g * G + rr;
                    int hin = h0 * S - 1 + r;
                    int hc = hin < 0 ? 0 : (hin >= HIN ? HIN - 1 : hin);
                    const u16* rowp = pl + (size_t)hc * WIN + (size_t)w0g * S;
                    R[rr][0] = ldu(rowp + offA);
                    R[rr][1] = ldu(rowp);
                    R[rr][2] = ldu(rowp + 2);
                    R[rr][3] = ldu(rowp + 4);
                    if constexpr (S == 2) R[rr][4] = ldu(rowp + 6);
                }
                // ---- compute pass: masks + fdot2 ----
#pragma unroll
                for (int rr = 0; rr < G; ++rr) {
                    const int r = g * G + rr;
                    const int hin = h0 * S - 1 + r;
                    uint32_t D0 = R[rr][0], D1 = R[rr][1];
                    uint32_t D2 = R[rr][2], D3 = R[rr][3];
                    uint32_t E4 = 0;
                    if constexpr (S == 2) E4 = R[rr][4];
                    // w-edge masks (per-thread)
                    D0 = (w0g > 0) ? D0 : 0u;
                    if constexpr (S == 1) D3 = (w0g + 4 < WIN) ? D3 : 0u;
                    // h-validity: only boundary rows can be OOB.
                    if constexpr (S == 1) {
                        if (r == 0 || r == ROWS - 1) {
                            const bool rv = (hin >= 0) && (hin < HIN);
                            if (!rv) { D0 = 0; D1 = 0; D2 = 0; D3 = 0; }
                        }
                    } else {
                        if (r == 0) {
                            const bool rv = (hin >= 0);
                            if (!rv) { D0 = 0; D1 = 0; D2 = 0; D3 = 0; E4 = 0; }
                        }
                    }
                    uint32_t PA[4], PB[4];
                    if constexpr (S == 1) {
                        const uint32_t m01 = mkp(D0, D1);  // (x-1,x0)
                        const uint32_t m12 = mkp(D1, D2);  // (x1,x2)
                        const uint32_t m23 = mkp(D2, D3);  // (x3,x4)
                        PA[0] = m01; PA[1] = D1; PA[2] = m12; PA[3] = D2;
                        PB[0] = m12; PB[1] = D2; PB[2] = m23; PB[3] = D3;
                    } else {
                        PA[0] = mkp(D0, D1); PA[1] = mkp(D1, D2);
                        PA[2] = mkp(D2, D3); PA[3] = mkp(D3, E4);
                        PB[0] = D1; PB[1] = D2; PB[2] = D3; PB[3] = E4;
                    }
#pragma unroll
                    for (int dl = 0; dl < DT; ++dl) {
                        const int kd = p - S * dl;         // folds after unroll
                        if (kd < 0 || kd > 2) continue;
#pragma unroll
                        for (int hh = 0; hh < 4; ++hh) {
                            const int kh = r - S * hh;     // folds after unroll
                            if (kh < 0 || kh > 2) continue;
                            const int t = kd * 3 + kh;
#pragma unroll
                            for (int k = 0; k < 4; ++k)
                                acc[dl][hh][k] = FDOT2(H2(PB[k]), KB[t],
                                                 FDOT2(H2(PA[k]), KA[t],
                                                       acc[dl][hh][k]));
                        }
                    }
                }
            }
        }

        const float bia = sDB[ci];
#pragma unroll
        for (int dl = 0; dl < DT; ++dl) {
#pragma unroll
            for (int hh = 0; hh < 4; ++hh) {
#pragma unroll
                for (int k = 0; k < 4; ++k) {
                    const float t = acc[dl][hh][k] + bia;
                    sT[((dl * 4 + hh) * 48 + wg * 4 + k) * CINP + ci] =
                        f2h(fmaxf(t, 0.1f * t));
                }
            }
        }
    }
    __syncthreads();

    // ---------------- phase 2: pointwise via f16 MFMA ----------------
    constexpr int NT = (COUT + 15) / 16;   // co tiles
    constexpr int KH = (CIN + 31) / 32;    // K=32 chunks
    constexpr int MTW = DT * 3;            // M-tiles per wave
    const int lane = tid & 63, wave = tid >> 6;
    const int m15 = lane & 15, q = lane >> 4;

    half8_t bf[NT][KH];
    float   pb[NT];
#pragma unroll
    for (int nt = 0; nt < NT; ++nt) {
        const int co = nt * 16 + m15;
        pb[nt] = (co < COUT) ? pw_b[co] : 0.f;
#pragma unroll
        for (int kh = 0; kh < KH; ++kh) {
            union { half8_t v; f16_t e[8]; } u;
#pragma unroll
            for (int j = 0; j < 8; ++j) {
                const int ci = kh * 32 + q * 8 + j;
                u.e[j] = (co < COUT && ci < CIN)
                         ? (f16_t)pw_w[co * CIN + ci] : (f16_t)0.f;
            }
            bf[nt][kh] = u.v;
        }
    }

    const size_t planeSz = (size_t)DO * HO * WO;
    for (int mt = wave * MTW; mt < (wave + 1) * MTW; ++mt) {
        const int dl  = mt / 12;
        const int rem = mt - dl * 12;
        const int hh  = rem / 3;
        const int w0  = (rem - hh * 3) * 16;
        if (d0 + dl >= DO) continue;           // tail guard

        const int pos0 = (dl * 4 + hh) * 48 + w0 + m15;
        const u16* ap = &sT[(size_t)pos0 * CINP];
        union { uint32_t u[4]; half8_t v; } af[KH];
#pragma unroll
        for (int kh = 0; kh < KH; ++kh) {
            const int ci0 = kh * 32 + q * 8;
            af[kh].u[0] = (ci0     < CIN) ? ldu(ap + ci0)     : 0u;
            af[kh].u[1] = (ci0 + 2 < CIN) ? ldu(ap + ci0 + 2) : 0u;
            af[kh].u[2] = (ci0 + 4 < CIN) ? ldu(ap + ci0 + 4) : 0u;
            af[kh].u[3] = (ci0 + 6 < CIN) ? ldu(ap + ci0 + 6) : 0u;
        }
#pragma unroll
        for (int nt = 0; nt < NT; ++nt) {
            f32x4 acc;
            acc.x = 0.f; acc.y = 0.f; acc.z = 0.f; acc.w = 0.f;
#pragma unroll
            for (int kh = 0; kh < KH; ++kh)
                acc = __builtin_amdgcn_mfma_f32_16x16x32_f16(
                          af[kh].v, bf[nt][kh], acc, 0, 0, 0);
            const int co = nt * 16 + m15;
            if (co < COUT) {
                const float bias = pb[nt];
                TOUT* yp = y + (size_t)b * COUT * planeSz + (size_t)co * planeSz
                             + (size_t)(d0 + dl) * HO * WO
                             + (size_t)(h0 + hh) * WO + wbase + w0 + q * 4;
                float s0 = acc.x + bias, s1 = acc.y + bias;
                float s2 = acc.z + bias, s3 = acc.w + bias;
                s0 = fmaxf(s0, 0.1f * s0); s1 = fmaxf(s1, 0.1f * s1);
                s2 = fmaxf(s2, 0.1f * s2); s3 = fmaxf(s3, 0.1f * s3);
                if constexpr (sizeof(TOUT) == 4) {
                    float4 o; o.x = s0; o.y = s1; o.z = s2; o.w = s3;
                    *(float4*)yp = o;
                } else {
                    ushort4 o;
                    o.x = f2h(s0); o.y = f2h(s1); o.z = f2h(s2); o.w = f2h(s3);
                    *(ushort4*)yp = o;
                }
            }
        }
    }
}

// Named wrappers with XCD-banded d-fastest decode:
// idx = band + 8*j, j = y + NY*(T>>3), T = x + NX*z  (band = T&7).
// Decode: j = idx>>3; y = j%NY; T = (idx&7) + 8*(j/NY); x = T%NX; z = T/NX.
__global__ __launch_bounds__(256) void fb1_dwpw(
        const u16* __restrict__ x, const float* __restrict__ dww,
        const float* __restrict__ dwb, const float* __restrict__ pww,
        const float* __restrict__ pwb, u16* __restrict__ y) {
    const int idx = blockIdx.x;                 // 5120 = 64x * 10y * 8z
    const int j = idx >> 3;
    const int by = j % 10;
    const int T = (idx & 7) + 8 * (j / 10);     // 0..511
    fused_impl<20, 20, 1, 2, 20, 64, 192, 20, 64, 192, u16>(
        x, dww, dwb, pww, pwb, y, T & 63, by, T >> 6);
}
__global__ __launch_bounds__(256) void fb2_dwpw(
        const u16* __restrict__ x, const float* __restrict__ dww,
        const float* __restrict__ dwb, const float* __restrict__ pww,
        const float* __restrict__ pwb, u16* __restrict__ y) {
    const int idx = blockIdx.x;                 // 640 = 16x * 5y * 8z
    const int j = idx >> 3;
    const int by = j % 5;
    const int T = (idx & 7) + 8 * (j / 5);      // 0..127
    fused_impl<20, 40, 2, 2, 20, 64, 192, 10, 32, 96, u16>(
        x, dww, dwb, pww, pwb, y, T & 15, by, T >> 4);
}
__global__ __launch_bounds__(256) void fb3_dwpw(
        const u16* __restrict__ x, const float* __restrict__ dww,
        const float* __restrict__ dwb, const float* __restrict__ pww,
        const float* __restrict__ pwb, u16* __restrict__ y) {
    const int idx = blockIdx.x;                 // 1280 = 16x * 10y * 8z
    const int j = idx >> 3;
    const int by = j % 10;
    const int T = (idx & 7) + 8 * (j / 10);     // 0..127
    fused_impl<40, 40, 1, 1, 10, 32, 96, 10, 32, 96, u16>(
        x, dww, dwb, pww, pwb, y, T & 15, by, T >> 4);
}
__global__ __launch_bounds__(256) void fb4_dwpw(
        const u16* __restrict__ x, const float* __restrict__ dww,
        const float* __restrict__ dwb, const float* __restrict__ pww,
        const float* __restrict__ pwb, float* __restrict__ y) {
    fused_impl<40, 80, 2, 1, 10, 32, 96, 5, 16, 48, float>(
        x, dww, dwb, pww, pwb, y, blockIdx.x, blockIdx.y, blockIdx.z);
}

// ---------------------------------------------------------------------------
extern "C" void kernel_launch(void* const* d_in, const int* in_sizes, int n_in,
                              void* d_out, int out_size, void* d_ws, size_t ws_size,
                              hipStream_t stream) {
    const float* rgb  = (const float*)d_in[0];
    const float* dep  = (const float*)d_in[1];
    const float* dw1w = (const float*)d_in[2];
    const float* dw1b = (const float*)d_in[3];
    const float* pw1w = (const float*)d_in[4];
    const float* pw1b = (const float*)d_in[5];
    const float* dw2w = (const float*)d_in[6];
    const float* dw2b = (const float*)d_in[7];
    const float* pw2w = (const float*)d_in[8];
    const float* pw2b = (const float*)d_in[9];
    const float* dw3w = (const float*)d_in[10];
    const float* dw3b = (const float*)d_in[11];
    const float* pw3w = (const float*)d_in[12];
    const float* pw3b = (const float*)d_in[13];
    const float* dw4w = (const float*)d_in[14];
    const float* dw4b = (const float*)d_in[15];
    const float* pw4w = (const float*)d_in[16];
    const float* pw4b = (const float*)d_in[17];

    const size_t HALF = 78643200;
    u16* corrO = (u16*)d_ws;
    u16* rgbT  = (u16*)((char*)d_ws + HALF);
    u16* depT  = (u16*)((char*)d_ws + HALF + 12582912);
    u16* b1o   = (u16*)((char*)d_ws + HALF);   // rgbT/depT dead by then
    u16* b2o   = (u16*)d_ws;                   // corrO dead by then
    u16* b3o   = (u16*)((char*)d_ws + HALF);   // b1o dead by then
    float* outp = (float*)d_out;

    transpose_f16<<<dim3(512, 2), 256, 0, stream>>>(rgb, dep, rgbT, depT);

    corr_mfma<<<dim3(2560), 256, 0, stream>>>(rgbT, depT, corrO);

    fb1_dwpw<<<dim3(5120), 256, 0, stream>>>(corrO, dw1w, dw1b, pw1w, pw1b, b1o);
    fb2_dwpw<<<dim3(640), 256, 0, stream>>>(b1o, dw2w, dw2b, pw2w, pw2b, b2o);
    fb3_dwpw<<<dim3(1280), 256, 0, stream>>>(b2o, dw3w, dw3b, pw3w, pw3b, b3o);
    fb4_dwpw<<<dim3(4, 5, 8), 256, 0, stream>>>(b3o, dw4w, dw4b, pw4w, pw4b, outp);
}

// Round 15
// 348.862 us; speedup vs baseline: 1.0748x; 1.0286x over previous
//
#include <hip/hip_runtime.h>
#include <cstdint>
#include <cstddef>

// ---------------------------------------------------------------------------
// feature_matching: corr(P=20, C=64) -> 4x (depthwise 3^3 + pointwise) blocks
//
// R15 = R12 restored exactly (best known: 353.1 us) with ONE bounded change:
// fb3 DT=1 -> DT=2 (d-halo fetch 3x -> 2x on its 19.7MB input; LDS 36.7KB
// -> 4 blk/CU x 4 waves = 16 waves/CU, equal to fb1's measured occupancy).
// R13's register-dbuf (spilled) and R14's fb XCD swizzle (fetch UP 157->179,
// dur flat -> fb1 not fetch-bound) are both reverted.
//
// ws layout (peak 157,286,400 B):
//   [0,        78.6MB): corrO (f16)        -> later b2o (f16, 19.7MB)
//   [78.6MB,  157.3MB): rgbT+depT (f16)    -> later b1o (f16, 78.6MB)
//                                          -> later b3o (f16, 19.7MB)
// ---------------------------------------------------------------------------

typedef unsigned short u16;
typedef _Float16 f16_t;
typedef __attribute__((ext_vector_type(2))) _Float16 half2_t;
typedef __attribute__((ext_vector_type(8))) _Float16 half8_t;
typedef __attribute__((ext_vector_type(4))) float f32x4;

static __device__ inline u16 f2h(float f) {
    union { f16_t h; u16 u; } v; v.h = (f16_t)f; return v.u;
}
static __device__ inline half2_t H2(uint32_t u) {
    union { uint32_t u; half2_t h; } v; v.u = u; return v.h;
}

#if __has_builtin(__builtin_amdgcn_fdot2)
static __device__ inline float FDOT2(half2_t a, half2_t b, float c) {
    return __builtin_amdgcn_fdot2(a, b, c, false);
}
#else
static __device__ inline float FDOT2(half2_t a, half2_t b, float c) {
    return fmaf((float)a.x, (float)b.x, fmaf((float)a.y, (float)b.y, c));
}
#endif

#if __has_builtin(__builtin_amdgcn_alignbit)
static __device__ inline uint32_t mkp(uint32_t lo, uint32_t hi) {
    return __builtin_amdgcn_alignbit(hi, lo, 16);   // (lo.hi16, hi.lo16)
}
#else
static __device__ inline uint32_t mkp(uint32_t lo, uint32_t hi) {
    return (lo >> 16) | (hi << 16);
}
#endif

static __device__ inline uint32_t ldu(const u16* p) { return *(const uint32_t*)p; }

// ---------------------------------------------------------------------------
// Prepass: (b,c,h,w) fp32 -> (b,h,w,c) f16, LDS tile transpose per (b,h).
// ---------------------------------------------------------------------------
__global__ __launch_bounds__(256) void transpose_f16(
        const float* __restrict__ rgb, const float* __restrict__ dep,
        u16* __restrict__ rgbT, u16* __restrict__ depT) {
    const int bh = blockIdx.x;
    const float* src = blockIdx.y ? dep : rgb;
    u16* dst = blockIdx.y ? depT : rgbT;
    const int tid = threadIdx.x;
    const int b = bh >> 6, h = bh & 63;

    __shared__ u16 S[64 * 194];

    const float* srcb = src + (size_t)b * 786432 + (size_t)h * 192;
#pragma unroll
    for (int it = 0; it < 12; ++it) {
        const int idx = it * 256 + tid;      // 3072 = 64c x 48 float4
        const int c = idx / 48, w4 = idx - c * 48;
        const float4 v = *(const float4*)(srcb + (size_t)c * 12288 + 4 * w4);
        u16* sp = &S[c * 194 + 4 * w4];
        sp[0] = f2h(v.x); sp[1] = f2h(v.y); sp[2] = f2h(v.z); sp[3] = f2h(v.w);
    }
    __syncthreads();
    u16* dstb = dst + (size_t)bh * 192 * 64;
#pragma unroll
    for (int it = 0; it < 12; ++it) {
        const int idx = it * 256 + tid;      // 3072 = 192w x 16 c4
        const int w = idx >> 4, c4 = idx & 15;
        ushort4 o;
        o.x = S[(4 * c4 + 0) * 194 + w];
        o.y = S[(4 * c4 + 1) * 194 + w];
        o.z = S[(4 * c4 + 2) * 194 + w];
        o.w = S[(4 * c4 + 3) * 194 + w];
        *(ushort4*)(dstb + (size_t)w * 64 + 4 * c4) = o;
    }
}

// ---------------------------------------------------------------------------
// corr v5 (unchanged from R12). Flat grid 2560, XCD-band swizzle.
// ---------------------------------------------------------------------------
__global__ __launch_bounds__(256) void corr_mfma(
        const u16* __restrict__ rgbT, const u16* __restrict__ depT,
        u16* __restrict__ out) {
    const int idx = blockIdx.x;
    const int band = idx & 7;
    const int j    = idx >> 3;
    const int dig  = j % 5;
    const int rest = j / 5;          // 0..63
    const int h    = band * 8 + (rest & 7);
    const int b    = rest >> 3;
    const int tid = threadIdx.x;
    const int lane = tid & 63, wave = tid >> 6;
    const int n = lane & 15, q = lane >> 4;
    const int w0base = wave * 48;

    __shared__ u16 D4[4][4080];      // per-di bank; addr = w*21 + (w>>2) + dj

    const u16* Abase = rgbT + (size_t)(b * 64 + h) * 12288;
    half8_t a0[3], a1[3];
#pragma unroll
    for (int t = 0; t < 3; ++t) {
        const half8_t* Ap = (const half8_t*)(Abase + (size_t)(w0base + t * 16 + n) * 64 + q * 8);
        a0[t] = Ap[0];               // c = q*8 .. q*8+7
        a1[t] = Ap[4];               // c += 32
    }

#pragma unroll
    for (int i = 0; i < 4; ++i) {
        const int di = dig * 4 + i;
        const int hd = h + di - 10;
        if (hd < 0 || hd >= 64) continue;    // block-uniform; zeros at readout

        const u16* Bbase = depT + (size_t)(b * 64 + hd) * 12288;
        half8_t B0[5], B1[5];
#pragma unroll
        for (int k = 0; k < 5; ++k) {
            const int u0 = w0base + (k - 1) * 16;
            if (u0 >= 0 && u0 <= 176) {      // wave-uniform
                const half8_t* Bp = (const half8_t*)(Bbase + (size_t)(u0 + n) * 64 + q * 8);
                B0[k] = Bp[0];
                B1[k] = Bp[4];
            } else {
                B0[k] = (half8_t)(f16_t)0.f;
                B1[k] = (half8_t)(f16_t)0.f;
            }
        }
#pragma unroll
        for (int t = 0; t < 3; ++t) {
            const int w0 = w0base + t * 16;
            f32x4 acc[3];
#pragma unroll
            for (int ut = 0; ut < 3; ++ut) {
                acc[ut].x = 0.f; acc[ut].y = 0.f; acc[ut].z = 0.f; acc[ut].w = 0.f;
            }
#pragma unroll
            for (int ut = 0; ut < 3; ++ut) {
                const int k = t + ut;        // array index for u-tile t+ut-1
                acc[ut] = __builtin_amdgcn_mfma_f32_16x16x32_f16(a0[t], B0[k], acc[ut], 0, 0, 0);
                acc[ut] = __builtin_amdgcn_mfma_f32_16x16x32_f16(a1[t], B1[k], acc[ut], 0, 0, 0);
            }
#pragma unroll
            for (int ut = 0; ut < 3; ++ut) {
#pragma unroll
                for (int r = 0; r < 4; ++r) {
                    const int dj = 16 * ut + n - 4 * q - r - 6;
                    const int w = w0 + 4 * q + r;
                    if (dj >= 0 && dj < 20)
                        D4[i][w * 21 + (w >> 2) + dj] = f2h(acc[ut][r]);
                }
            }
        }
    }

#pragma unroll
    for (int i = 0; i < 4; ++i) {
        const int di = dig * 4 + i;
        const int hd = h + di - 10;
        const bool valid = (hd >= 0) && (hd < 64);   // block-uniform
        u16* outb = out + ((size_t)((b * 20 + di) * 20) * 64 + h) * 192;
#pragma unroll
        for (int it = 0; it < 4; ++it) {
            const int item = it * 64 + lane;
            if (item < 240) {
                const int dj = item / 12;
                const int w4 = wave * 12 + (item - dj * 12);
                ushort4 o;
                if (valid) {
                    const int base = 85 * w4 + dj;   // (4*w4+j)*21 + w4 + dj
                    o.x = D4[i][base];
                    o.y = D4[i][base + 21];
                    o.z = D4[i][base + 42];
                    o.w = D4[i][base + 63];
                } else {
                    o = make_ushort4(0, 0, 0, 0);
                }
                *(ushort4*)(outb + (size_t)dj * 12288 + 4 * w4) = o;
            }
        }
    }
}

// ---------------------------------------------------------------------------
// Fused block v9 (R12 body). Phase 1: load-pass (batched, unconditional,
// h-clamped) + compute-pass (masks + fdot2). Phase 2: f16 MFMA pointwise.
// ---------------------------------------------------------------------------
template<int CIN, int COUT, int S, int DT, int DIN, int HIN, int WIN,
         int DO, int HO, int WO, typename TOUT>
static __device__ __forceinline__ void fused_impl(
        const u16* __restrict__ x,
        const float* __restrict__ dw_w, const float* __restrict__ dw_b,
        const float* __restrict__ pw_w, const float* __restrict__ pw_b,
        TOUT* __restrict__ y) {
    static_assert(WO % 48 == 0 && HO % 4 == 0, "tile divisibility");
    constexpr int CINP = (CIN == 20) ? 22 : 42;    // odd dword stride
    constexpr int NTASK = CIN * 12;
    constexpr int WT = WO / 48;
    constexpr int NP = S * (DT - 1) + 3;
    constexpr int ROWS = 3 * S + 3;                // 6 or 9
    constexpr int NL = (S == 1) ? 4 : 5;           // dwords per row
    constexpr int G  = (S == 1) ? 6 : 3;           // rows per load batch
    constexpr int NG = ROWS / G;

    const int wt = blockIdx.x % WT;
    const int ht = blockIdx.x / WT;
    const int d0 = blockIdx.y * DT;
    const int b  = blockIdx.z;
    const int tid = threadIdx.x;
    const int h0 = ht * 4;
    const int wbase = wt * 48;

    __shared__ float sDW[CIN * 27];
    __shared__ float sDB[CIN];
    __shared__ u16   sT[DT * 4 * 48 * CINP + 16];

    for (int i = tid; i < CIN * 27; i += 256) sDW[i] = dw_w[i];
    for (int i = tid; i < CIN; i += 256) sDB[i] = dw_b[i];
    __syncthreads();

    // ---------------- phase 1: depthwise via fdot2 ----------------
    for (int idx = tid; idx < NTASK; idx += 256) {
        const int ci = idx / 12;
        const int wg = idx - ci * 12;
        const int w0g = wbase + wg * 4;
        const int offA = (w0g > 0) ? -2 : 0;   // keeps corner load in-bounds

        half2_t KA[9], KB[9];
#pragma unroll
        for (int t = 0; t < 9; ++t) {
            const int kd = t / 3, kh = t - 3 * kd;
            const float k0 = sDW[ci * 27 + kd * 9 + kh * 3 + 0];
            const float k1 = sDW[ci * 27 + kd * 9 + kh * 3 + 1];
            const float k2 = sDW[ci * 27 + kd * 9 + kh * 3 + 2];
            half2_t a; a.x = (f16_t)k0; a.y = (f16_t)k1; KA[t] = a;
            half2_t bb;
            if constexpr (S == 1) { bb.x = (f16_t)k2; bb.y = (f16_t)0.f; }
            else                  { bb.x = (f16_t)0.f; bb.y = (f16_t)k2; }
            KB[t] = bb;
        }

        float acc[DT][4][4];
#pragma unroll
        for (int dl = 0; dl < DT; ++dl)
#pragma unroll
            for (int a = 0; a < 4; ++a)
#pragma unroll
                for (int c = 0; c < 4; ++c) acc[dl][a][c] = 0.f;

        const u16* plane0 = x + (size_t)(b * CIN + ci) * DIN * HIN * WIN;
#pragma unroll
        for (int p = 0; p < NP; ++p) {
            const int din = S * d0 - 1 + p;
            if (din < 0 || din >= DIN) continue;       // block-uniform, rare
            const u16* pl = plane0 + (size_t)din * HIN * WIN;
#pragma unroll
            for (int g = 0; g < NG; ++g) {
                // ---- load pass: all rows of this batch, unconditional ----
                uint32_t R[G][NL];
#pragma unroll
                for (int rr = 0; rr < G; ++rr) {
                    const int r = g * G + rr;
                    int hin = h0 * S - 1 + r;
                    int hc = hin < 0 ? 0 : (hin >= HIN ? HIN - 1 : hin);
                    const u16* rowp = pl + (size_t)hc * WIN + (size_t)w0g * S;
                    R[rr][0] = ldu(rowp + offA);
                    R[rr][1] = ldu(rowp);
                    R[rr][2] = ldu(rowp + 2);
                    R[rr][3] = ldu(rowp + 4);
                    if constexpr (S == 2) R[rr][4] = ldu(rowp + 6);
                }
                // ---- compute pass: masks + fdot2 ----
#pragma unroll
                for (int rr = 0; rr < G; ++rr) {
                    const int r = g * G + rr;
                    const int hin = h0 * S - 1 + r;
                    uint32_t D0 = R[rr][0], D1 = R[rr][1];
                    uint32_t D2 = R[rr][2], D3 = R[rr][3];
                    uint32_t E4 = 0;
                    if constexpr (S == 2) E4 = R[rr][4];
                    // w-edge masks (per-thread)
                    D0 = (w0g > 0) ? D0 : 0u;
                    if constexpr (S == 1) D3 = (w0g + 4 < WIN) ? D3 : 0u;
                    // h-validity: only boundary rows can be OOB.
                    if constexpr (S == 1) {
                        if (r == 0 || r == ROWS - 1) {
                            const bool rv = (hin >= 0) && (hin < HIN);
                            if (!rv) { D0 = 0; D1 = 0; D2 = 0; D3 = 0; }
                        }
                    } else {
                        if (r == 0) {
                            const bool rv = (hin >= 0);
                            if (!rv) { D0 = 0; D1 = 0; D2 = 0; D3 = 0; E4 = 0; }
                        }
                    }
                    uint32_t PA[4], PB[4];
                    if constexpr (S == 1) {
                        const uint32_t m01 = mkp(D0, D1);  // (x-1,x0)
                        const uint32_t m12 = mkp(D1, D2);  // (x1,x2)
                        const uint32_t m23 = mkp(D2, D3);  // (x3,x4)
                        PA[0] = m01; PA[1] = D1; PA[2] = m12; PA[3] = D2;
                        PB[0] = m12; PB[1] = D2; PB[2] = m23; PB[3] = D3;
                    } else {
                        PA[0] = mkp(D0, D1); PA[1] = mkp(D1, D2);
                        PA[2] = mkp(D2, D3); PA[3] = mkp(D3, E4);
                        PB[0] = D1; PB[1] = D2; PB[2] = D3; PB[3] = E4;
                    }
#pragma unroll
                    for (int dl = 0; dl < DT; ++dl) {
                        const int kd = p - S * dl;         // folds after unroll
                        if (kd < 0 || kd > 2) continue;
#pragma unroll
                        for (int hh = 0; hh < 4; ++hh) {
                            const int kh = r - S * hh;     // folds after unroll
                            if (kh < 0 || kh > 2) continue;
                            const int t = kd * 3 + kh;
#pragma unroll
                            for (int k = 0; k < 4; ++k)
                                acc[dl][hh][k] = FDOT2(H2(PB[k]), KB[t],
                                                 FDOT2(H2(PA[k]), KA[t],
                                                       acc[dl][hh][k]));
                        }
                    }
                }
            }
        }

        const float bia = sDB[ci];
#pragma unroll
        for (int dl = 0; dl < DT; ++dl) {
#pragma unroll
            for (int hh = 0; hh < 4; ++hh) {
#pragma unroll
                for (int k = 0; k < 4; ++k) {
                    const float t = acc[dl][hh][k] + bia;
                    sT[((dl * 4 + hh) * 48 + wg * 4 + k) * CINP + ci] =
                        f2h(fmaxf(t, 0.1f * t));
                }
            }
        }
    }
    __syncthreads();

    // ---------------- phase 2: pointwise via f16 MFMA ----------------
    constexpr int NT = (COUT + 15) / 16;   // co tiles
    constexpr int KH = (CIN + 31) / 32;    // K=32 chunks
    constexpr int MTW = DT * 3;            // M-tiles per wave
    const int lane = tid & 63, wave = tid >> 6;
    const int m15 = lane & 15, q = lane >> 4;

    half8_t bf[NT][KH];
    float   pb[NT];
#pragma unroll
    for (int nt = 0; nt < NT; ++nt) {
        const int co = nt * 16 + m15;
        pb[nt] = (co < COUT) ? pw_b[co] : 0.f;
#pragma unroll
        for (int kh = 0; kh < KH; ++kh) {
            union { half8_t v; f16_t e[8]; } u;
#pragma unroll
            for (int j = 0; j < 8; ++j) {
                const int ci = kh * 32 + q * 8 + j;
                u.e[j] = (co < COUT && ci < CIN)
                         ? (f16_t)pw_w[co * CIN + ci] : (f16_t)0.f;
            }
            bf[nt][kh] = u.v;
        }
    }

    const size_t planeSz = (size_t)DO * HO * WO;
    for (int mt = wave * MTW; mt < (wave + 1) * MTW; ++mt) {
        const int dl  = mt / 12;
        const int rem = mt - dl * 12;
        const int hh  = rem / 3;
        const int w0  = (rem - hh * 3) * 16;
        if (d0 + dl >= DO) continue;           // tail guard

        const int pos0 = (dl * 4 + hh) * 48 + w0 + m15;
        const u16* ap = &sT[(size_t)pos0 * CINP];
        union { uint32_t u[4]; half8_t v; } af[KH];
#pragma unroll
        for (int kh = 0; kh < KH; ++kh) {
            const int ci0 = kh * 32 + q * 8;
            af[kh].u[0] = (ci0     < CIN) ? ldu(ap + ci0)     : 0u;
            af[kh].u[1] = (ci0 + 2 < CIN) ? ldu(ap + ci0 + 2) : 0u;
            af[kh].u[2] = (ci0 + 4 < CIN) ? ldu(ap + ci0 + 4) : 0u;
            af[kh].u[3] = (ci0 + 6 < CIN) ? ldu(ap + ci0 + 6) : 0u;
        }
#pragma unroll
        for (int nt = 0; nt < NT; ++nt) {
            f32x4 acc;
            acc.x = 0.f; acc.y = 0.f; acc.z = 0.f; acc.w = 0.f;
#pragma unroll
            for (int kh = 0; kh < KH; ++kh)
                acc = __builtin_amdgcn_mfma_f32_16x16x32_f16(
                          af[kh].v, bf[nt][kh], acc, 0, 0, 0);
            const int co = nt * 16 + m15;
            if (co < COUT) {
                const float bias = pb[nt];
                TOUT* yp = y + (size_t)b * COUT * planeSz + (size_t)co * planeSz
                             + (size_t)(d0 + dl) * HO * WO
                             + (size_t)(h0 + hh) * WO + wbase + w0 + q * 4;
                float s0 = acc.x + bias, s1 = acc.y + bias;
                float s2 = acc.z + bias, s3 = acc.w + bias;
                s0 = fmaxf(s0, 0.1f * s0); s1 = fmaxf(s1, 0.1f * s1);
                s2 = fmaxf(s2, 0.1f * s2); s3 = fmaxf(s3, 0.1f * s3);
                if constexpr (sizeof(TOUT) == 4) {
                    float4 o; o.x = s0; o.y = s1; o.z = s2; o.w = s3;
                    *(float4*)yp = o;
                } else {
                    ushort4 o;
                    o.x = f2h(s0); o.y = f2h(s1); o.z = f2h(s2); o.w = f2h(s3);
                    *(ushort4*)yp = o;
                }
            }
        }
    }
}

// Named wrappers -> per-stage visibility in rocprof.
__global__ __launch_bounds__(256) void fb1_dwpw(
        const u16* __restrict__ x, const float* __restrict__ dww,
        const float* __restrict__ dwb, const float* __restrict__ pww,
        const float* __restrict__ pwb, u16* __restrict__ y) {
    fused_impl<20, 20, 1, 2, 20, 64, 192, 20, 64, 192, u16>(x, dww, dwb, pww, pwb, y);
}
__global__ __launch_bounds__(256) void fb2_dwpw(
        const u16* __restrict__ x, const float* __restrict__ dww,
        const float* __restrict__ dwb, const float* __restrict__ pww,
        const float* __restrict__ pwb, u16* __restrict__ y) {
    fused_impl<20, 40, 2, 2, 20, 64, 192, 10, 32, 96, u16>(x, dww, dwb, pww, pwb, y);
}
__global__ __launch_bounds__(256) void fb3_dwpw(
        const u16* __restrict__ x, const float* __restrict__ dww,
        const float* __restrict__ dwb, const float* __restrict__ pww,
        const float* __restrict__ pwb, u16* __restrict__ y) {
    fused_impl<40, 40, 1, 2, 10, 32, 96, 10, 32, 96, u16>(x, dww, dwb, pww, pwb, y);
}
__global__ __launch_bounds__(256) void fb4_dwpw(
        const u16* __restrict__ x, const float* __restrict__ dww,
        const float* __restrict__ dwb, const float* __restrict__ pww,
        const float* __restrict__ pwb, float* __restrict__ y) {
    fused_impl<40, 80, 2, 1, 10, 32, 96, 5, 16, 48, float>(x, dww, dwb, pww, pwb, y);
}

// ---------------------------------------------------------------------------
extern "C" void kernel_launch(void* const* d_in, const int* in_sizes, int n_in,
                              void* d_out, int out_size, void* d_ws, size_t ws_size,
                              hipStream_t stream) {
    const float* rgb  = (const float*)d_in[0];
    const float* dep  = (const float*)d_in[1];
    const float* dw1w = (const float*)d_in[2];
    const float* dw1b = (const float*)d_in[3];
    const float* pw1w = (const float*)d_in[4];
    const float* pw1b = (const float*)d_in[5];
    const float* dw2w = (const float*)d_in[6];
    const float* dw2b = (const float*)d_in[7];
    const float* pw2w = (const float*)d_in[8];
    const float* pw2b = (const float*)d_in[9];
    const float* dw3w = (const float*)d_in[10];
    const float* dw3b = (const float*)d_in[11];
    const float* pw3w = (const float*)d_in[12];
    const float* pw3b = (const float*)d_in[13];
    const float* dw4w = (const float*)d_in[14];
    const float* dw4b = (const float*)d_in[15];
    const float* pw4w = (const float*)d_in[16];
    const float* pw4b = (const float*)d_in[17];

    const size_t HALF = 78643200;
    u16* corrO = (u16*)d_ws;
    u16* rgbT  = (u16*)((char*)d_ws + HALF);
    u16* depT  = (u16*)((char*)d_ws + HALF + 12582912);
    u16* b1o   = (u16*)((char*)d_ws + HALF);   // rgbT/depT dead by then
    u16* b2o   = (u16*)d_ws;                   // corrO dead by then
    u16* b3o   = (u16*)((char*)d_ws + HALF);   // b1o dead by then
    float* outp = (float*)d_out;

    transpose_f16<<<dim3(512, 2), 256, 0, stream>>>(rgb, dep, rgbT, depT);

    corr_mfma<<<dim3(2560), 256, 0, stream>>>(rgbT, depT, corrO);

    fb1_dwpw<<<dim3(64, 10, 8), 256, 0, stream>>>(corrO, dw1w, dw1b, pw1w, pw1b, b1o);
    fb2_dwpw<<<dim3(16, 5, 8), 256, 0, stream>>>(b1o, dw2w, dw2b, pw2w, pw2b, b2o);
    fb3_dwpw<<<dim3(16, 5, 8), 256, 0, stream>>>(b2o, dw3w, dw3b, pw3w, pw3b, b3o);
    fb4_dwpw<<<dim3(4, 5, 8), 256, 0, stream>>>(b3o, dw4w, dw4b, pw4w, pw4b, outp);
}

// Round 16
// 346.045 us; speedup vs baseline: 1.0836x; 1.0081x over previous
//
#include <hip/hip_runtime.h>
#include <cstdint>
#include <cstddef>

// ---------------------------------------------------------------------------
// feature_matching: corr(P=20, C=64) -> 4x (depthwise 3^3 + pointwise) blocks
//
// R16 = R15 with ONE change: fb1 DT=2 -> DT=4. Amortizes plane loads/masks
// over 4 d-outputs (loads 3.0->2.25/out, d-halo 2x->1.5x, FETCH 158->~120MB).
// acc[4][4][4]=64 VGPR -> ~105 total (4 waves/SIMD), sT 33.8KB -> 4 blk/CU
// = same ~16 waves/CU as measured today. Single guarded loop retained (the
// R7 dual-path and R13 manual-dbuf spill mechanisms are absent).
// Revert trigger: WRITE_SIZE jump (spill) or occ < 40%.
//
// ws layout (peak 157,286,400 B):
//   [0,        78.6MB): corrO (f16)        -> later b2o (f16, 19.7MB)
//   [78.6MB,  157.3MB): rgbT+depT (f16)    -> later b1o (f16, 78.6MB)
//                                          -> later b3o (f16, 19.7MB)
// ---------------------------------------------------------------------------

typedef unsigned short u16;
typedef _Float16 f16_t;
typedef __attribute__((ext_vector_type(2))) _Float16 half2_t;
typedef __attribute__((ext_vector_type(8))) _Float16 half8_t;
typedef __attribute__((ext_vector_type(4))) float f32x4;

static __device__ inline u16 f2h(float f) {
    union { f16_t h; u16 u; } v; v.h = (f16_t)f; return v.u;
}
static __device__ inline half2_t H2(uint32_t u) {
    union { uint32_t u; half2_t h; } v; v.u = u; return v.h;
}

#if __has_builtin(__builtin_amdgcn_fdot2)
static __device__ inline float FDOT2(half2_t a, half2_t b, float c) {
    return __builtin_amdgcn_fdot2(a, b, c, false);
}
#else
static __device__ inline float FDOT2(half2_t a, half2_t b, float c) {
    return fmaf((float)a.x, (float)b.x, fmaf((float)a.y, (float)b.y, c));
}
#endif

#if __has_builtin(__builtin_amdgcn_alignbit)
static __device__ inline uint32_t mkp(uint32_t lo, uint32_t hi) {
    return __builtin_amdgcn_alignbit(hi, lo, 16);   // (lo.hi16, hi.lo16)
}
#else
static __device__ inline uint32_t mkp(uint32_t lo, uint32_t hi) {
    return (lo >> 16) | (hi << 16);
}
#endif

static __device__ inline uint32_t ldu(const u16* p) { return *(const uint32_t*)p; }

// ---------------------------------------------------------------------------
// Prepass: (b,c,h,w) fp32 -> (b,h,w,c) f16, LDS tile transpose per (b,h).
// ---------------------------------------------------------------------------
__global__ __launch_bounds__(256) void transpose_f16(
        const float* __restrict__ rgb, const float* __restrict__ dep,
        u16* __restrict__ rgbT, u16* __restrict__ depT) {
    const int bh = blockIdx.x;
    const float* src = blockIdx.y ? dep : rgb;
    u16* dst = blockIdx.y ? depT : rgbT;
    const int tid = threadIdx.x;
    const int b = bh >> 6, h = bh & 63;

    __shared__ u16 S[64 * 194];

    const float* srcb = src + (size_t)b * 786432 + (size_t)h * 192;
#pragma unroll
    for (int it = 0; it < 12; ++it) {
        const int idx = it * 256 + tid;      // 3072 = 64c x 48 float4
        const int c = idx / 48, w4 = idx - c * 48;
        const float4 v = *(const float4*)(srcb + (size_t)c * 12288 + 4 * w4);
        u16* sp = &S[c * 194 + 4 * w4];
        sp[0] = f2h(v.x); sp[1] = f2h(v.y); sp[2] = f2h(v.z); sp[3] = f2h(v.w);
    }
    __syncthreads();
    u16* dstb = dst + (size_t)bh * 192 * 64;
#pragma unroll
    for (int it = 0; it < 12; ++it) {
        const int idx = it * 256 + tid;      // 3072 = 192w x 16 c4
        const int w = idx >> 4, c4 = idx & 15;
        ushort4 o;
        o.x = S[(4 * c4 + 0) * 194 + w];
        o.y = S[(4 * c4 + 1) * 194 + w];
        o.z = S[(4 * c4 + 2) * 194 + w];
        o.w = S[(4 * c4 + 3) * 194 + w];
        *(ushort4*)(dstb + (size_t)w * 64 + 4 * c4) = o;
    }
}

// ---------------------------------------------------------------------------
// corr v5 (unchanged from R12). Flat grid 2560, XCD-band swizzle.
// ---------------------------------------------------------------------------
__global__ __launch_bounds__(256) void corr_mfma(
        const u16* __restrict__ rgbT, const u16* __restrict__ depT,
        u16* __restrict__ out) {
    const int idx = blockIdx.x;
    const int band = idx & 7;
    const int j    = idx >> 3;
    const int dig  = j % 5;
    const int rest = j / 5;          // 0..63
    const int h    = band * 8 + (rest & 7);
    const int b    = rest >> 3;
    const int tid = threadIdx.x;
    const int lane = tid & 63, wave = tid >> 6;
    const int n = lane & 15, q = lane >> 4;
    const int w0base = wave * 48;

    __shared__ u16 D4[4][4080];      // per-di bank; addr = w*21 + (w>>2) + dj

    const u16* Abase = rgbT + (size_t)(b * 64 + h) * 12288;
    half8_t a0[3], a1[3];
#pragma unroll
    for (int t = 0; t < 3; ++t) {
        const half8_t* Ap = (const half8_t*)(Abase + (size_t)(w0base + t * 16 + n) * 64 + q * 8);
        a0[t] = Ap[0];               // c = q*8 .. q*8+7
        a1[t] = Ap[4];               // c += 32
    }

#pragma unroll
    for (int i = 0; i < 4; ++i) {
        const int di = dig * 4 + i;
        const int hd = h + di - 10;
        if (hd < 0 || hd >= 64) continue;    // block-uniform; zeros at readout

        const u16* Bbase = depT + (size_t)(b * 64 + hd) * 12288;
        half8_t B0[5], B1[5];
#pragma unroll
        for (int k = 0; k < 5; ++k) {
            const int u0 = w0base + (k - 1) * 16;
            if (u0 >= 0 && u0 <= 176) {      // wave-uniform
                const half8_t* Bp = (const half8_t*)(Bbase + (size_t)(u0 + n) * 64 + q * 8);
                B0[k] = Bp[0];
                B1[k] = Bp[4];
            } else {
                B0[k] = (half8_t)(f16_t)0.f;
                B1[k] = (half8_t)(f16_t)0.f;
            }
        }
#pragma unroll
        for (int t = 0; t < 3; ++t) {
            const int w0 = w0base + t * 16;
            f32x4 acc[3];
#pragma unroll
            for (int ut = 0; ut < 3; ++ut) {
                acc[ut].x = 0.f; acc[ut].y = 0.f; acc[ut].z = 0.f; acc[ut].w = 0.f;
            }
#pragma unroll
            for (int ut = 0; ut < 3; ++ut) {
                const int k = t + ut;        // array index for u-tile t+ut-1
                acc[ut] = __builtin_amdgcn_mfma_f32_16x16x32_f16(a0[t], B0[k], acc[ut], 0, 0, 0);
                acc[ut] = __builtin_amdgcn_mfma_f32_16x16x32_f16(a1[t], B1[k], acc[ut], 0, 0, 0);
            }
#pragma unroll
            for (int ut = 0; ut < 3; ++ut) {
#pragma unroll
                for (int r = 0; r < 4; ++r) {
                    const int dj = 16 * ut + n - 4 * q - r - 6;
                    const int w = w0 + 4 * q + r;
                    if (dj >= 0 && dj < 20)
                        D4[i][w * 21 + (w >> 2) + dj] = f2h(acc[ut][r]);
                }
            }
        }
    }

#pragma unroll
    for (int i = 0; i < 4; ++i) {
        const int di = dig * 4 + i;
        const int hd = h + di - 10;
        const bool valid = (hd >= 0) && (hd < 64);   // block-uniform
        u16* outb = out + ((size_t)((b * 20 + di) * 20) * 64 + h) * 192;
#pragma unroll
        for (int it = 0; it < 4; ++it) {
            const int item = it * 64 + lane;
            if (item < 240) {
                const int dj = item / 12;
                const int w4 = wave * 12 + (item - dj * 12);
                ushort4 o;
                if (valid) {
                    const int base = 85 * w4 + dj;   // (4*w4+j)*21 + w4 + dj
                    o.x = D4[i][base];
                    o.y = D4[i][base + 21];
                    o.z = D4[i][base + 42];
                    o.w = D4[i][base + 63];
                } else {
                    o = make_ushort4(0, 0, 0, 0);
                }
                *(ushort4*)(outb + (size_t)dj * 12288 + 4 * w4) = o;
            }
        }
    }
}

// ---------------------------------------------------------------------------
// Fused block v9 (R12 body). Phase 1: load-pass (batched, unconditional,
// h-clamped) + compute-pass (masks + fdot2). Phase 2: f16 MFMA pointwise.
// ---------------------------------------------------------------------------
template<int CIN, int COUT, int S, int DT, int DIN, int HIN, int WIN,
         int DO, int HO, int WO, typename TOUT>
static __device__ __forceinline__ void fused_impl(
        const u16* __restrict__ x,
        const float* __restrict__ dw_w, const float* __restrict__ dw_b,
        const float* __restrict__ pw_w, const float* __restrict__ pw_b,
        TOUT* __restrict__ y) {
    static_assert(WO % 48 == 0 && HO % 4 == 0, "tile divisibility");
    constexpr int CINP = (CIN == 20) ? 22 : 42;    // odd dword stride
    constexpr int NTASK = CIN * 12;
    constexpr int WT = WO / 48;
    constexpr int NP = S * (DT - 1) + 3;
    constexpr int ROWS = 3 * S + 3;                // 6 or 9
    constexpr int NL = (S == 1) ? 4 : 5;           // dwords per row
    constexpr int G  = (S == 1) ? 6 : 3;           // rows per load batch
    constexpr int NG = ROWS / G;

    const int wt = blockIdx.x % WT;
    const int ht = blockIdx.x / WT;
    const int d0 = blockIdx.y * DT;
    const int b  = blockIdx.z;
    const int tid = threadIdx.x;
    const int h0 = ht * 4;
    const int wbase = wt * 48;

    __shared__ float sDW[CIN * 27];
    __shared__ float sDB[CIN];
    __shared__ u16   sT[DT * 4 * 48 * CINP + 16];

    for (int i = tid; i < CIN * 27; i += 256) sDW[i] = dw_w[i];
    for (int i = tid; i < CIN; i += 256) sDB[i] = dw_b[i];
    __syncthreads();

    // ---------------- phase 1: depthwise via fdot2 ----------------
    for (int idx = tid; idx < NTASK; idx += 256) {
        const int ci = idx / 12;
        const int wg = idx - ci * 12;
        const int w0g = wbase + wg * 4;
        const int offA = (w0g > 0) ? -2 : 0;   // keeps corner load in-bounds

        half2_t KA[9], KB[9];
#pragma unroll
        for (int t = 0; t < 9; ++t) {
            const int kd = t / 3, kh = t - 3 * kd;
            const float k0 = sDW[ci * 27 + kd * 9 + kh * 3 + 0];
            const float k1 = sDW[ci * 27 + kd * 9 + kh * 3 + 1];
            const float k2 = sDW[ci * 27 + kd * 9 + kh * 3 + 2];
            half2_t a; a.x = (f16_t)k0; a.y = (f16_t)k1; KA[t] = a;
            half2_t bb;
            if constexpr (S == 1) { bb.x = (f16_t)k2; bb.y = (f16_t)0.f; }
            else                  { bb.x = (f16_t)0.f; bb.y = (f16_t)k2; }
            KB[t] = bb;
        }

        float acc[DT][4][4];
#pragma unroll
        for (int dl = 0; dl < DT; ++dl)
#pragma unroll
            for (int a = 0; a < 4; ++a)
#pragma unroll
                for (int c = 0; c < 4; ++c) acc[dl][a][c] = 0.f;

        const u16* plane0 = x + (size_t)(b * CIN + ci) * DIN * HIN * WIN;
#pragma unroll
        for (int p = 0; p < NP; ++p) {
            const int din = S * d0 - 1 + p;
            if (din < 0 || din >= DIN) continue;       // block-uniform, rare
            const u16* pl = plane0 + (size_t)din * HIN * WIN;
#pragma unroll
            for (int g = 0; g < NG; ++g) {
                // ---- load pass: all rows of this batch, unconditional ----
                uint32_t R[G][NL];
#pragma unroll
                for (int rr = 0; rr < G; ++rr) {
                    const int r = g * G + rr;
                    int hin = h0 * S - 1 + r;
                    int hc = hin < 0 ? 0 : (hin >= HIN ? HIN - 1 : hin);
                    const u16* rowp = pl + (size_t)hc * WIN + (size_t)w0g * S;
                    R[rr][0] = ldu(rowp + offA);
                    R[rr][1] = ldu(rowp);
                    R[rr][2] = ldu(rowp + 2);
                    R[rr][3] = ldu(rowp + 4);
                    if constexpr (S == 2) R[rr][4] = ldu(rowp + 6);
                }
                // ---- compute pass: masks + fdot2 ----
#pragma unroll
                for (int rr = 0; rr < G; ++rr) {
                    const int r = g * G + rr;
                    const int hin = h0 * S - 1 + r;
                    uint32_t D0 = R[rr][0], D1 = R[rr][1];
                    uint32_t D2 = R[rr][2], D3 = R[rr][3];
                    uint32_t E4 = 0;
                    if constexpr (S == 2) E4 = R[rr][4];
                    // w-edge masks (per-thread)
                    D0 = (w0g > 0) ? D0 : 0u;
                    if constexpr (S == 1) D3 = (w0g + 4 < WIN) ? D3 : 0u;
                    // h-validity: only boundary rows can be OOB.
                    if constexpr (S == 1) {
                        if (r == 0 || r == ROWS - 1) {
                            const bool rv = (hin >= 0) && (hin < HIN);
                            if (!rv) { D0 = 0; D1 = 0; D2 = 0; D3 = 0; }
                        }
                    } else {
                        if (r == 0) {
                            const bool rv = (hin >= 0);
                            if (!rv) { D0 = 0; D1 = 0; D2 = 0; D3 = 0; E4 = 0; }
                        }
                    }
                    uint32_t PA[4], PB[4];
                    if constexpr (S == 1) {
                        const uint32_t m01 = mkp(D0, D1);  // (x-1,x0)
                        const uint32_t m12 = mkp(D1, D2);  // (x1,x2)
                        const uint32_t m23 = mkp(D2, D3);  // (x3,x4)
                        PA[0] = m01; PA[1] = D1; PA[2] = m12; PA[3] = D2;
                        PB[0] = m12; PB[1] = D2; PB[2] = m23; PB[3] = D3;
                    } else {
                        PA[0] = mkp(D0, D1); PA[1] = mkp(D1, D2);
                        PA[2] = mkp(D2, D3); PA[3] = mkp(D3, E4);
                        PB[0] = D1; PB[1] = D2; PB[2] = D3; PB[3] = E4;
                    }
#pragma unroll
                    for (int dl = 0; dl < DT; ++dl) {
                        const int kd = p - S * dl;         // folds after unroll
                        if (kd < 0 || kd > 2) continue;
#pragma unroll
                        for (int hh = 0; hh < 4; ++hh) {
                            const int kh = r - S * hh;     // folds after unroll
                            if (kh < 0 || kh > 2) continue;
                            const int t = kd * 3 + kh;
#pragma unroll
                            for (int k = 0; k < 4; ++k)
                                acc[dl][hh][k] = FDOT2(H2(PB[k]), KB[t],
                                                 FDOT2(H2(PA[k]), KA[t],
                                                       acc[dl][hh][k]));
                        }
                    }
                }
            }
        }

        const float bia = sDB[ci];
#pragma unroll
        for (int dl = 0; dl < DT; ++dl) {
#pragma unroll
            for (int hh = 0; hh < 4; ++hh) {
#pragma unroll
                for (int k = 0; k < 4; ++k) {
                    const float t = acc[dl][hh][k] + bia;
                    sT[((dl * 4 + hh) * 48 + wg * 4 + k) * CINP + ci] =
                        f2h(fmaxf(t, 0.1f * t));
                }
            }
        }
    }
    __syncthreads();

    // ---------------- phase 2: pointwise via f16 MFMA ----------------
    constexpr int NT = (COUT + 15) / 16;   // co tiles
    constexpr int KH = (CIN + 31) / 32;    // K=32 chunks
    constexpr int MTW = DT * 3;            // M-tiles per wave
    const int lane = tid & 63, wave = tid >> 6;
    const int m15 = lane & 15, q = lane >> 4;

    half8_t bf[NT][KH];
    float   pb[NT];
#pragma unroll
    for (int nt = 0; nt < NT; ++nt) {
        const int co = nt * 16 + m15;
        pb[nt] = (co < COUT) ? pw_b[co] : 0.f;
#pragma unroll
        for (int kh = 0; kh < KH; ++kh) {
            union { half8_t v; f16_t e[8]; } u;
#pragma unroll
            for (int j = 0; j < 8; ++j) {
                const int ci = kh * 32 + q * 8 + j;
                u.e[j] = (co < COUT && ci < CIN)
                         ? (f16_t)pw_w[co * CIN + ci] : (f16_t)0.f;
            }
            bf[nt][kh] = u.v;
        }
    }

    const size_t planeSz = (size_t)DO * HO * WO;
    for (int mt = wave * MTW; mt < (wave + 1) * MTW; ++mt) {
        const int dl  = mt / 12;
        const int rem = mt - dl * 12;
        const int hh  = rem / 3;
        const int w0  = (rem - hh * 3) * 16;
        if (d0 + dl >= DO) continue;           // tail guard

        const int pos0 = (dl * 4 + hh) * 48 + w0 + m15;
        const u16* ap = &sT[(size_t)pos0 * CINP];
        union { uint32_t u[4]; half8_t v; } af[KH];
#pragma unroll
        for (int kh = 0; kh < KH; ++kh) {
            const int ci0 = kh * 32 + q * 8;
            af[kh].u[0] = (ci0     < CIN) ? ldu(ap + ci0)     : 0u;
            af[kh].u[1] = (ci0 + 2 < CIN) ? ldu(ap + ci0 + 2) : 0u;
            af[kh].u[2] = (ci0 + 4 < CIN) ? ldu(ap + ci0 + 4) : 0u;
            af[kh].u[3] = (ci0 + 6 < CIN) ? ldu(ap + ci0 + 6) : 0u;
        }
#pragma unroll
        for (int nt = 0; nt < NT; ++nt) {
            f32x4 acc;
            acc.x = 0.f; acc.y = 0.f; acc.z = 0.f; acc.w = 0.f;
#pragma unroll
            for (int kh = 0; kh < KH; ++kh)
                acc = __builtin_amdgcn_mfma_f32_16x16x32_f16(
                          af[kh].v, bf[nt][kh], acc, 0, 0, 0);
            const int co = nt * 16 + m15;
            if (co < COUT) {
                const float bias = pb[nt];
                TOUT* yp = y + (size_t)b * COUT * planeSz + (size_t)co * planeSz
                             + (size_t)(d0 + dl) * HO * WO
                             + (size_t)(h0 + hh) * WO + wbase + w0 + q * 4;
                float s0 = acc.x + bias, s1 = acc.y + bias;
                float s2 = acc.z + bias, s3 = acc.w + bias;
                s0 = fmaxf(s0, 0.1f * s0); s1 = fmaxf(s1, 0.1f * s1);
                s2 = fmaxf(s2, 0.1f * s2); s3 = fmaxf(s3, 0.1f * s3);
                if constexpr (sizeof(TOUT) == 4) {
                    float4 o; o.x = s0; o.y = s1; o.z = s2; o.w = s3;
                    *(float4*)yp = o;
                } else {
                    ushort4 o;
                    o.x = f2h(s0); o.y = f2h(s1); o.z = f2h(s2); o.w = f2h(s3);
                    *(ushort4*)yp = o;
                }
            }
        }
    }
}

// Named wrappers -> per-stage visibility in rocprof.
__global__ __launch_bounds__(256) void fb1_dwpw(
        const u16* __restrict__ x, const float* __restrict__ dww,
        const float* __restrict__ dwb, const float* __restrict__ pww,
        const float* __restrict__ pwb, u16* __restrict__ y) {
    fused_impl<20, 20, 1, 4, 20, 64, 192, 20, 64, 192, u16>(x, dww, dwb, pww, pwb, y);
}
__global__ __launch_bounds__(256) void fb2_dwpw(
        const u16* __restrict__ x, const float* __restrict__ dww,
        const float* __restrict__ dwb, const float* __restrict__ pww,
        const float* __restrict__ pwb, u16* __restrict__ y) {
    fused_impl<20, 40, 2, 2, 20, 64, 192, 10, 32, 96, u16>(x, dww, dwb, pww, pwb, y);
}
__global__ __launch_bounds__(256) void fb3_dwpw(
        const u16* __restrict__ x, const float* __restrict__ dww,
        const float* __restrict__ dwb, const float* __restrict__ pww,
        const float* __restrict__ pwb, u16* __restrict__ y) {
    fused_impl<40, 40, 1, 2, 10, 32, 96, 10, 32, 96, u16>(x, dww, dwb, pww, pwb, y);
}
__global__ __launch_bounds__(256) void fb4_dwpw(
        const u16* __restrict__ x, const float* __restrict__ dww,
        const float* __restrict__ dwb, const float* __restrict__ pww,
        const float* __restrict__ pwb, float* __restrict__ y) {
    fused_impl<40, 80, 2, 1, 10, 32, 96, 5, 16, 48, float>(x, dww, dwb, pww, pwb, y);
}

// ---------------------------------------------------------------------------
extern "C" void kernel_launch(void* const* d_in, const int* in_sizes, int n_in,
                              void* d_out, int out_size, void* d_ws, size_t ws_size,
                              hipStream_t stream) {
    const float* rgb  = (const float*)d_in[0];
    const float* dep  = (const float*)d_in[1];
    const float* dw1w = (const float*)d_in[2];
    const float* dw1b = (const float*)d_in[3];
    const float* pw1w = (const float*)d_in[4];
    const float* pw1b = (const float*)d_in[5];
    const float* dw2w = (const float*)d_in[6];
    const float* dw2b = (const float*)d_in[7];
    const float* pw2w = (const float*)d_in[8];
    const float* pw2b = (const float*)d_in[9];
    const float* dw3w = (const float*)d_in[10];
    const float* dw3b = (const float*)d_in[11];
    const float* pw3w = (const float*)d_in[12];
    const float* pw3b = (const float*)d_in[13];
    const float* dw4w = (const float*)d_in[14];
    const float* dw4b = (const float*)d_in[15];
    const float* pw4w = (const float*)d_in[16];
    const float* pw4b = (const float*)d_in[17];

    const size_t HALF = 78643200;
    u16* corrO = (u16*)d_ws;
    u16* rgbT  = (u16*)((char*)d_ws + HALF);
    u16* depT  = (u16*)((char*)d_ws + HALF + 12582912);
    u16* b1o   = (u16*)((char*)d_ws + HALF);   // rgbT/depT dead by then
    u16* b2o   = (u16*)d_ws;                   // corrO dead by then
    u16* b3o   = (u16*)((char*)d_ws + HALF);   // b1o dead by then
    float* outp = (float*)d_out;

    transpose_f16<<<dim3(512, 2), 256, 0, stream>>>(rgb, dep, rgbT, depT);

    corr_mfma<<<dim3(2560), 256, 0, stream>>>(rgbT, depT, corrO);

    fb1_dwpw<<<dim3(64, 5, 8), 256, 0, stream>>>(corrO, dw1w, dw1b, pw1w, pw1b, b1o);
    fb2_dwpw<<<dim3(16, 5, 8), 256, 0, stream>>>(b1o, dw2w, dw2b, pw2w, pw2b, b2o);
    fb3_dwpw<<<dim3(16, 5, 8), 256, 0, stream>>>(b2o, dw3w, dw3b, pw3w, pw3b, b3o);
    fb4_dwpw<<<dim3(4, 5, 8), 256, 0, stream>>>(b3o, dw4w, dw4b, pw4w, pw4b, outp);
}